// Round 6
// baseline (27.388 us; speedup 1.0000x reference)
//
#include <hip/hip_runtime.h>
#include <hip/hip_fp16.h>

// BilateralSliceApply: grid [4,12,8,16,16] f32, guide [4,1024,1024] f32,
// image [4,3,1024,1024] f32 -> out [4,3,1024,1024] f32.
//
// One block per image row. Row's y-lerped grid slab staged in LDS as fp16
// Z-PAIRS: s[x][z*12+c] = half2(A[z][c], A[min(z+1,7)][c]). One ds_read_b128
// then yields 4 channels x BOTH z-corners -> 6 b128/pixel instead of 12
// (the LDS read pipe was the measured floor). z-lerp/x-lerp in fp32.
// Pixel->lane mapping p = j*256 + t keeps each wave within <=2 x-cells ->
// ~2 distinct lines per bank-quad on every b128 (near-conflict-free).

static constexpr int C_ = 12, D_ = 8, GH_ = 16, GW_ = 16;
static constexpr int H_ = 1024, W_ = 1024;
static constexpr int HW_ = H_ * W_;
static constexpr int XS = D_ * C_ + 4;   // 100 half2 slots per x (400 B, 16B-mult)

__global__ __launch_bounds__(256) void bsa_h2_kernel(
    const float* __restrict__ grid,   // [B][C][D][GH][GW]
    const float* __restrict__ guide,  // [B][H][W]
    const float* __restrict__ image,  // [B][3][H][W]
    float* __restrict__ out)          // [B][3][H][W]
{
    __shared__ __half2 s[GW_ * XS];   // 6.4 KB

    const int bid = blockIdx.x;       // = b*H + y
    const int y = bid & (H_ - 1);
    const int b = bid >> 10;
    const int t = threadIdx.x;

    // ---- y interpolation factors (uniform across block) ----
    const float gyc = (y + 0.5f) * (1.0f / 64.0f) - 0.5f;
    const float fy = floorf(gyc);
    const float ty = gyc - fy;
    const int iy = (int)fy;
    const int y0 = min(max(iy, 0), GH_ - 1);
    const int y1 = min(max(iy + 1, 0), GH_ - 1);

    // ---- slab global loads first (threads 0..191): x=t&15, c=t>>4, z=0..7 ----
    const int sx = t & 15, sc = t >> 4;
    float sv0[8], sv1[8];
    const float* gb = grid + b * (C_ * D_ * GH_ * GW_);
    if (t < 192) {
        const int base = sc * (D_ * GH_ * GW_) + sx;
#pragma unroll
        for (int z = 0; z < 8; ++z) {
            sv0[z] = gb[base + z * (GH_ * GW_) + y0 * GW_];
            sv1[z] = gb[base + z * (GH_ * GW_) + y1 * GW_];
        }
    }

    // ---- issue all pixel loads (in flight under slab write) ----
    const float* gdp = guide + (size_t)bid * W_;
    const float* imp = image + (size_t)b * 3 * HW_ + (size_t)y * W_;
    float gz4[4], r4[4], g4[4], b4[4];
#pragma unroll
    for (int j = 0; j < 4; ++j) {
        const int p = j * 256 + t;
        gz4[j] = gdp[p];
        r4[j]  = imp[p];
        g4[j]  = imp[HW_ + p];
        b4[j]  = imp[2 * HW_ + p];
    }

    // ---- y-lerp, build z-pairs, write fp16 slab ----
    if (t < 192) {
        float a[8];
#pragma unroll
        for (int z = 0; z < 8; ++z)
            a[z] = sv0[z] + ty * (sv1[z] - sv0[z]);
        const int sl = sx * XS + sc;
#pragma unroll
        for (int z = 0; z < 8; ++z) {
            const int zn = (z < 7) ? z + 1 : 7;
            s[sl + z * C_] = __halves2half2(__float2half_rn(a[z]),
                                            __float2half_rn(a[zn]));
        }
    }
    __syncthreads();

    // ---- compute: 4 strided pixels per thread ----
    float* const ob = out + (size_t)b * 3 * HW_ + (size_t)y * W_;
#pragma unroll
    for (int j = 0; j < 4; ++j) {
        const int p = j * 256 + t;

        const float gxc = (p + 0.5f) * (1.0f / 64.0f) - 0.5f;
        const float fx = floorf(gxc);
        const float tx = gxc - fx;
        const int ix = (int)fx;
        const int x0 = min(max(ix, 0), GW_ - 1);
        const int x1 = min(max(ix + 1, 0), GW_ - 1);

        const float gz = gz4[j] * (float)D_ - 0.5f;
        const float fz = floorf(gz);
        const int iz = (int)fz;
        // iz in [-1, 7]; iz==-1 -> exact A[0] via tz=0; iz==7 handled by
        // pair construction (A7,A7).
        const float tz = (iz < 0) ? 0.0f : (gz - fz);
        const int z0 = max(iz, 0);

        const __half2* q0 = s + x0 * XS + z0 * C_;
        const __half2* q1 = s + x1 * XS + z0 * C_;

        const float rv = r4[j], gv = g4[j], bv = b4[j];
        float res[3];

#pragma unroll
        for (int k = 0; k < 3; ++k) {
            float4 u0 = *(const float4*)(q0 + 4 * k);   // 4 half2 = 4 ch (z0,z1)
            float4 u1 = *(const float4*)(q1 + 4 * k);
            float c4[4];
#pragma unroll
            for (int e = 0; e < 4; ++e) {
                const float ue0 = (e == 0) ? u0.x : (e == 1) ? u0.y : (e == 2) ? u0.z : u0.w;
                const float ue1 = (e == 0) ? u1.x : (e == 1) ? u1.y : (e == 2) ? u1.z : u1.w;
                const float2 f0 = __half22float2(__builtin_bit_cast(__half2, ue0));
                const float2 f1 = __half22float2(__builtin_bit_cast(__half2, ue1));
                const float v0 = fmaf(tz, f0.y - f0.x, f0.x);   // z-lerp @ x0
                const float v1 = fmaf(tz, f1.y - f1.x, f1.x);   // z-lerp @ x1
                c4[e] = fmaf(tx, v1 - v0, v0);                  // x-lerp
            }
            res[k] = fmaf(c4[0], rv, fmaf(c4[1], gv, fmaf(c4[2], bv, c4[3])));
        }

#pragma unroll
        for (int k = 0; k < 3; ++k)
            ob[(size_t)k * HW_ + p] = res[k];
    }
}

extern "C" void kernel_launch(void* const* d_in, const int* in_sizes, int n_in,
                              void* d_out, int out_size, void* d_ws, size_t ws_size,
                              hipStream_t stream) {
    const float* grid  = (const float*)d_in[0];
    const float* guide = (const float*)d_in[1];
    const float* image = (const float*)d_in[2];
    float* out = (float*)d_out;

    bsa_h2_kernel<<<4 * H_, 256, 0, stream>>>(grid, guide, image, out);
}

// Round 7
// 25.446 us; speedup vs baseline: 1.0764x; 1.0764x over previous
//
#include <hip/hip_runtime.h>

// BilateralSliceApply: grid [4,12,8,16,16] f32, guide [4,1024,1024] f32,
// image [4,3,1024,1024] f32 -> out [4,3,1024,1024] f32.
//
// One block per image row; y-lerped grid slab (16 x-cells * 8 z * 12 c) in
// LDS. Pixel->lane mapping p = (j*256 + t + 32) & 1023 aligns every wave to
// an x-cell band [64k+32, 64k+96): (x0,x1) is WAVE-UNIFORM, so each
// ds_read_b128 touches one x-slab where quad index (25*x0 + 3*z + k) mod 8
// is bijective in z -> exactly 1 line per bank-quad, 8-lane broadcast,
// fully conflict-free (round 4's 2-lines-per-quad pattern measured ~1.6x).

static constexpr int C_ = 12, D_ = 8, GH_ = 16, GW_ = 16;
static constexpr int H_ = 1024, W_ = 1024;
static constexpr int HW_ = H_ * W_;
static constexpr int XS = D_ * C_ + 4;   // 100 floats; 16B-aligned x-slabs

__global__ __launch_bounds__(256) void bsa_xcell_kernel(
    const float* __restrict__ grid,   // [B][C][D][GH][GW]
    const float* __restrict__ guide,  // [B][H][W]
    const float* __restrict__ image,  // [B][3][H][W]
    float* __restrict__ out)          // [B][3][H][W]
{
    __shared__ float s[GW_ * XS];     // 6.4 KB

    const int bid = blockIdx.x;       // = b*H + y
    const int y = bid & (H_ - 1);
    const int b = bid >> 10;
    const int t = threadIdx.x;

    // ---- y interpolation factors (uniform across block) ----
    const float gyc = (y + 0.5f) * (1.0f / 64.0f) - 0.5f;
    const float fy = floorf(gyc);
    const float ty = gyc - fy;
    const int iy = (int)fy;
    const int y0 = min(max(iy, 0), GH_ - 1);
    const int y1 = min(max(iy + 1, 0), GH_ - 1);

    // ---- issue slab global loads FIRST (threads 0..191) ----
    // mapping: x = t&15, c = t>>4, z unrolled; reads 64B-coalesced per 16
    // lanes; LDS write bank = (4x + c + 12z) mod 32 -> 2-way b32 (free).
    const int sx = t & 15, sc = t >> 4;
    float sv0[8], sv1[8];
    const float* gb = grid + b * (C_ * D_ * GH_ * GW_);
    if (t < 192) {
        const int base = sc * (D_ * GH_ * GW_) + sx;
#pragma unroll
        for (int z = 0; z < 8; ++z) {
            sv0[z] = gb[base + z * (GH_ * GW_) + y0 * GW_];
            sv1[z] = gb[base + z * (GH_ * GW_) + y1 * GW_];
        }
    }

    // ---- issue all pixel loads (stay in flight under slab write) ----
    // p = (j*256 + t + 32) & 1023: wave-aligned to x-cell bands.
    const float* gdp = guide + (size_t)bid * W_;
    const float* imp = image + (size_t)b * 3 * HW_ + (size_t)y * W_;
    float gz4[4], r4[4], g4[4], b4[4];
#pragma unroll
    for (int j = 0; j < 4; ++j) {
        const int p = (j * 256 + t + 32) & (W_ - 1);
        gz4[j] = gdp[p];
        r4[j]  = imp[p];
        g4[j]  = imp[HW_ + p];
        b4[j]  = imp[2 * HW_ + p];
    }

    // ---- y-lerp slab into LDS ----
    if (t < 192) {
#pragma unroll
        for (int z = 0; z < 8; ++z)
            s[sx * XS + z * C_ + sc] = sv0[z] + ty * (sv1[z] - sv0[z]);
    }
    __syncthreads();

    // ---- compute: 4 x-cell-aligned pixels per thread ----
    float* const ob = out + (size_t)b * 3 * HW_ + (size_t)y * W_;
#pragma unroll
    for (int j = 0; j < 4; ++j) {
        const int p = (j * 256 + t + 32) & (W_ - 1);

        const float gxc = (p + 0.5f) * (1.0f / 64.0f) - 0.5f;
        const float fx = floorf(gxc);
        const float tx = gxc - fx;
        const int ix = (int)fx;
        const int x0 = min(max(ix, 0), GW_ - 1);      // wave-uniform
        const int x1 = min(max(ix + 1, 0), GW_ - 1);  // wave-uniform

        const float gz = gz4[j] * (float)D_ - 0.5f;
        const float fz = floorf(gz);
        const float tz = gz - fz;
        const int iz = (int)fz;
        const int z0 = min(max(iz, 0), D_ - 1);
        const int z1 = min(max(iz + 1, 0), D_ - 1);

        const float w00 = (1.f - tx) * (1.f - tz);
        const float w01 = (1.f - tx) * tz;
        const float w10 = tx * (1.f - tz);
        const float w11 = tx * tz;

        const float* p00 = s + x0 * XS + z0 * C_;
        const float* p01 = s + x0 * XS + z1 * C_;
        const float* p10 = s + x1 * XS + z0 * C_;
        const float* p11 = s + x1 * XS + z1 * C_;

        const float rv = r4[j], gv = g4[j], bv = b4[j];

#pragma unroll
        for (int k = 0; k < 3; ++k) {
            float4 a0 = *(const float4*)(p00 + 4 * k);
            float4 a1 = *(const float4*)(p01 + 4 * k);
            float4 a2 = *(const float4*)(p10 + 4 * k);
            float4 a3 = *(const float4*)(p11 + 4 * k);
            float cx = w00 * a0.x + w01 * a1.x + w10 * a2.x + w11 * a3.x;
            float cy = w00 * a0.y + w01 * a1.y + w10 * a2.y + w11 * a3.y;
            float cz = w00 * a0.z + w01 * a1.z + w10 * a2.z + w11 * a3.z;
            float cw = w00 * a0.w + w01 * a1.w + w10 * a2.w + w11 * a3.w;
            ob[(size_t)k * HW_ + p] = cx * rv + cy * gv + cz * bv + cw;
        }
    }
}

extern "C" void kernel_launch(void* const* d_in, const int* in_sizes, int n_in,
                              void* d_out, int out_size, void* d_ws, size_t ws_size,
                              hipStream_t stream) {
    const float* grid  = (const float*)d_in[0];
    const float* guide = (const float*)d_in[1];
    const float* image = (const float*)d_in[2];
    float* out = (float*)d_out;

    bsa_xcell_kernel<<<4 * H_, 256, 0, stream>>>(grid, guide, image, out);
}

// Round 8
// 24.513 us; speedup vs baseline: 1.1173x; 1.0380x over previous
//
#include <hip/hip_runtime.h>

// BilateralSliceApply: grid [4,12,8,16,16] f32, guide [4,1024,1024] f32,
// image [4,3,1024,1024] f32 -> out [4,3,1024,1024] f32.
//
// One block per image row; y-lerped grid slab in LDS as fp16 Z-PAIRS:
// dword s[x*100 + z*12 + c] = half2(a[c,z], a[c,min(z+1,7)]).
// Bilinear (x,z) interp via v_dot2_f32_f16: the 4 corner weights become two
// half2s, and each channel is 2 fdot2 ops (f32 accumulate, no cvt):
//   acc_c = fdot2(h[x1,z0,c], wB, fdot2(h[x0,z0,c], wA, 0))
// -> 6 ds_read_b128 + 24 fdot2 per pixel (vs 12 b128 + 48 FMA in fp32 ver),
// cutting BOTH the LDS pipe and VALU with a SHORTER dependency chain.
// Pixel->lane mapping p = j*256 + t (64 consecutive px per wave instr,
// <=2 distinct lines per bank-quad - measured free).

typedef _Float16 h2 __attribute__((ext_vector_type(2)));

static __device__ __forceinline__ float fdot2f(h2 a, h2 b, float c) {
#if __has_builtin(__builtin_amdgcn_fdot2)
    return __builtin_amdgcn_fdot2(a, b, c, false);
#else
    return (float)a.x * (float)b.x + (float)a.y * (float)b.y + c;
#endif
}

static __device__ __forceinline__ h2 bch2(unsigned u) {
    return __builtin_bit_cast(h2, u);
}

static constexpr int C_ = 12, D_ = 8, GH_ = 16, GW_ = 16;
static constexpr int H_ = 1024, W_ = 1024;
static constexpr int HW_ = H_ * W_;
static constexpr int XS = D_ * C_ + 4;   // 100 dword slots per x-slab (16B-mult)

__global__ __launch_bounds__(256) void bsa_dot2_kernel(
    const float* __restrict__ grid,   // [B][C][D][GH][GW]
    const float* __restrict__ guide,  // [B][H][W]
    const float* __restrict__ image,  // [B][3][H][W]
    float* __restrict__ out)          // [B][3][H][W]
{
    __shared__ unsigned s[GW_ * XS];  // 6.4 KB; dword = half2 z-pair

    const int bid = blockIdx.x;       // = b*H + y
    const int y = bid & (H_ - 1);
    const int b = bid >> 10;
    const int t = threadIdx.x;

    // ---- y interpolation factors (uniform across block) ----
    const float gyc = (y + 0.5f) * (1.0f / 64.0f) - 0.5f;
    const float fy = floorf(gyc);
    const float ty = gyc - fy;
    const int iy = (int)fy;
    const int y0 = min(max(iy, 0), GH_ - 1);
    const int y1 = min(max(iy + 1, 0), GH_ - 1);

    // ---- slab global loads first (threads 0..191): x=t&15, c=t>>4, z=0..7 ----
    const int sx = t & 15, sc = t >> 4;
    float sv0[8], sv1[8];
    const float* gb = grid + b * (C_ * D_ * GH_ * GW_);
    if (t < 192) {
        const int base = sc * (D_ * GH_ * GW_) + sx;
#pragma unroll
        for (int z = 0; z < 8; ++z) {
            sv0[z] = gb[base + z * (GH_ * GW_) + y0 * GW_];
            sv1[z] = gb[base + z * (GH_ * GW_) + y1 * GW_];
        }
    }

    // ---- issue all pixel loads (stay in flight under slab write) ----
    const float* gdp = guide + (size_t)bid * W_;
    const float* imp = image + (size_t)b * 3 * HW_ + (size_t)y * W_;
    float gz4[4], r4[4], g4[4], b4[4];
#pragma unroll
    for (int j = 0; j < 4; ++j) {
        const int p = j * 256 + t;
        gz4[j] = gdp[p];
        r4[j]  = imp[p];
        g4[j]  = imp[HW_ + p];
        b4[j]  = imp[2 * HW_ + p];
    }

    // ---- y-lerp, build fp16 z-pairs, write slab ----
    if (t < 192) {
        float a[8];
#pragma unroll
        for (int z = 0; z < 8; ++z)
            a[z] = sv0[z] + ty * (sv1[z] - sv0[z]);
        const int sl = sx * XS + sc;
#pragma unroll
        for (int z = 0; z < 8; ++z) {
            const int zn = (z < 7) ? z + 1 : 7;
            h2 v = {(_Float16)a[z], (_Float16)a[zn]};
            s[sl + z * C_] = __builtin_bit_cast(unsigned, v);
        }
    }
    __syncthreads();

    // ---- compute: 4 strided pixels per thread ----
    float* const ob = out + (size_t)b * 3 * HW_ + (size_t)y * W_;
#pragma unroll
    for (int j = 0; j < 4; ++j) {
        const int p = j * 256 + t;

        const float gxc = (p + 0.5f) * (1.0f / 64.0f) - 0.5f;
        const float fx = floorf(gxc);
        const float tx = gxc - fx;
        const int ix = (int)fx;
        const int x0 = min(max(ix, 0), GW_ - 1);
        const int x1 = min(max(ix + 1, 0), GW_ - 1);

        const float gz = gz4[j] * (float)D_ - 0.5f;
        const float fz = floorf(gz);
        const int iz = (int)fz;          // in [-1, 7]
        const float tz = (iz < 0) ? 0.0f : (gz - fz);   // iz==-1 -> exact a[0]
        const int z0 = max(iz, 0);       // iz==7 handled by (a7,a7) pair

        // bilinear weights as two half2s for fdot2
        const float omtx = 1.0f - tx, omtz = 1.0f - tz;
        const h2 wA = {(_Float16)(omtz * omtx), (_Float16)(tz * omtx)};
        const h2 wB = {(_Float16)(omtz * tx),   (_Float16)(tz * tx)};

        const uint4* q0 = (const uint4*)(s + x0 * XS + z0 * C_);  // 16B-aligned
        const uint4* q1 = (const uint4*)(s + x1 * XS + z0 * C_);
        const uint4 A0 = q0[0], A1 = q0[1], A2 = q0[2];
        const uint4 B0 = q1[0], B1 = q1[1], B2 = q1[2];

        float acc[12];
        acc[0]  = fdot2f(bch2(B0.x), wB, fdot2f(bch2(A0.x), wA, 0.0f));
        acc[1]  = fdot2f(bch2(B0.y), wB, fdot2f(bch2(A0.y), wA, 0.0f));
        acc[2]  = fdot2f(bch2(B0.z), wB, fdot2f(bch2(A0.z), wA, 0.0f));
        acc[3]  = fdot2f(bch2(B0.w), wB, fdot2f(bch2(A0.w), wA, 0.0f));
        acc[4]  = fdot2f(bch2(B1.x), wB, fdot2f(bch2(A1.x), wA, 0.0f));
        acc[5]  = fdot2f(bch2(B1.y), wB, fdot2f(bch2(A1.y), wA, 0.0f));
        acc[6]  = fdot2f(bch2(B1.z), wB, fdot2f(bch2(A1.z), wA, 0.0f));
        acc[7]  = fdot2f(bch2(B1.w), wB, fdot2f(bch2(A1.w), wA, 0.0f));
        acc[8]  = fdot2f(bch2(B2.x), wB, fdot2f(bch2(A2.x), wA, 0.0f));
        acc[9]  = fdot2f(bch2(B2.y), wB, fdot2f(bch2(A2.y), wA, 0.0f));
        acc[10] = fdot2f(bch2(B2.z), wB, fdot2f(bch2(A2.z), wA, 0.0f));
        acc[11] = fdot2f(bch2(B2.w), wB, fdot2f(bch2(A2.w), wA, 0.0f));

        const float rv = r4[j], gv = g4[j], bv = b4[j];
        ob[0 * (size_t)HW_ + p] = fmaf(acc[0], rv, fmaf(acc[1],  gv, fmaf(acc[2],  bv, acc[3])));
        ob[1 * (size_t)HW_ + p] = fmaf(acc[4], rv, fmaf(acc[5],  gv, fmaf(acc[6],  bv, acc[7])));
        ob[2 * (size_t)HW_ + p] = fmaf(acc[8], rv, fmaf(acc[9],  gv, fmaf(acc[10], bv, acc[11])));
    }
}

extern "C" void kernel_launch(void* const* d_in, const int* in_sizes, int n_in,
                              void* d_out, int out_size, void* d_ws, size_t ws_size,
                              hipStream_t stream) {
    const float* grid  = (const float*)d_in[0];
    const float* guide = (const float*)d_in[1];
    const float* image = (const float*)d_in[2];
    float* out = (float*)d_out;
    (void)d_ws; (void)ws_size;

    bsa_dot2_kernel<<<4 * H_, 256, 0, stream>>>(grid, guide, image, out);
}